// Round 1
// baseline (334.824 us; speedup 1.0000x reference)
//
#include <hip/hip_runtime.h>
#include <hip/hip_bf16.h>

// Problem constants
#define NB 8
#define NC 256      // C
#define CI 128      // Ci
#define NH 1024     // 32*32
#define NL 4096     // 64*64

// ---------------------------------------------------------------------------
// A: phi[b,i,n] = sum_c Wp[i,c] xh[b,c,n] + bp[i];  g likewise with Wg,bg.
// grid (8, 8 i-chunks of 16, 8 n-chunks of 128), 256 threads.
__global__ __launch_bounds__(256) void proj_hi(
    const float* __restrict__ xh,
    const float* __restrict__ Wg, const float* __restrict__ bg,
    const float* __restrict__ Wp, const float* __restrict__ bp,
    float* __restrict__ phi, float* __restrict__ g) {
  __shared__ float Wp_s[16][256];
  __shared__ float Wg_s[16][256];
  const int b = blockIdx.x, i0 = blockIdx.y * 16, n0 = blockIdx.z * 128;
  const int t = threadIdx.x;
  // stage 16x256 of each weight
  #pragma unroll
  for (int k = 0; k < 4; ++k) {
    int f = t + k * 256;                 // [0,1024) float4 slots
    int row = f >> 6, q = (f & 63) << 2;
    *(float4*)&Wp_s[row][q] = *(const float4*)&Wp[(i0 + row) * 256 + q];
    *(float4*)&Wg_s[row][q] = *(const float4*)&Wg[(i0 + row) * 256 + q];
  }
  __syncthreads();
  const int n = t & 127, isub = (t >> 7) * 8;   // 2 groups of 8 i's
  float accP[8], accG[8];
  #pragma unroll
  for (int r = 0; r < 8; ++r) { accP[r] = 0.f; accG[r] = 0.f; }
  const float* xcol = xh + (size_t)b * NC * NH + n0 + n;
  for (int c = 0; c < 256; c += 4) {
    float x0 = xcol[(size_t)(c + 0) * NH];
    float x1 = xcol[(size_t)(c + 1) * NH];
    float x2 = xcol[(size_t)(c + 2) * NH];
    float x3 = xcol[(size_t)(c + 3) * NH];
    #pragma unroll
    for (int r = 0; r < 8; ++r) {
      float4 wp = *(const float4*)&Wp_s[isub + r][c];
      float4 wg = *(const float4*)&Wg_s[isub + r][c];
      accP[r] += wp.x * x0 + wp.y * x1 + wp.z * x2 + wp.w * x3;
      accG[r] += wg.x * x0 + wg.y * x1 + wg.z * x2 + wg.w * x3;
    }
  }
  #pragma unroll
  for (int r = 0; r < 8; ++r) {
    int i = i0 + isub + r;
    phi[((size_t)b * CI + i) * NH + n0 + n] = accP[r] + bp[i];
    g  [((size_t)b * CI + i) * NH + n0 + n] = accG[r] + bg[i];
  }
}

// ---------------------------------------------------------------------------
// B: Mpart[b,kc,i,j] = sum_{n in chunk} phi[b,i,n] * g[b,j,n]
// grid (8, 16 k-chunks of 64), 256 threads. LDS 64KB, XOR-swizzled 16B granules.
__global__ __launch_bounds__(256) void mk_mpart(
    const float* __restrict__ phi, const float* __restrict__ g,
    float* __restrict__ Mpart) {
  __shared__ float ps[128 * 64];
  __shared__ float gs[128 * 64];
  const int b = blockIdx.x, n0 = blockIdx.y * 64;
  const int t = threadIdx.x;
  #pragma unroll
  for (int k = 0; k < 8; ++k) {
    int f = t + k * 256;                 // [0,2048): row + 16B granule
    int row = f >> 4, q = f & 15;
    int qs = q ^ ((row >> 3) & 7);       // swizzle to spread banks on reads
    *(float4*)&ps[row * 64 + qs * 4] =
        *(const float4*)&phi[((size_t)b * CI + row) * NH + n0 + q * 4];
    *(float4*)&gs[row * 64 + qs * 4] =
        *(const float4*)&g[((size_t)b * CI + row) * NH + n0 + q * 4];
  }
  __syncthreads();
  const int ti = (t >> 4) * 8, tj = (t & 15) * 8;
  float acc[8][8] = {};
  for (int q = 0; q < 16; ++q) {
    float4 pa[8], gb[8];
    #pragma unroll
    for (int r = 0; r < 8; ++r) {
      int rp = ti + r, rg = tj + r;
      pa[r] = *(const float4*)&ps[rp * 64 + (q ^ ((rp >> 3) & 7)) * 4];
      gb[r] = *(const float4*)&gs[rg * 64 + (q ^ ((rg >> 3) & 7)) * 4];
    }
    #pragma unroll
    for (int r = 0; r < 8; ++r)
      #pragma unroll
      for (int s = 0; s < 8; ++s)
        acc[r][s] += pa[r].x * gb[s].x + pa[r].y * gb[s].y +
                     pa[r].z * gb[s].z + pa[r].w * gb[s].w;
  }
  float* mp = Mpart + ((size_t)(b * 16 + blockIdx.y) * 128) * 128;
  #pragma unroll
  for (int r = 0; r < 8; ++r)
    #pragma unroll
    for (int s = 0; s < 8; s += 4) {
      float4 v = make_float4(acc[r][s], acc[r][s + 1], acc[r][s + 2], acc[r][s + 3]);
      *(float4*)&mp[(ti + r) * 128 + tj + s] = v;
    }
}

// ---------------------------------------------------------------------------
// reduce 16 partials, fold in 1/Nh
__global__ __launch_bounds__(256) void mreduce(
    const float* __restrict__ Mpart, float* __restrict__ M) {
  int idx = blockIdx.x * 256 + threadIdx.x;   // 131072 outputs
  int b = idx >> 14, r = idx & 16383;
  const float* p = Mpart + (size_t)b * 16 * 16384 + r;
  float s = 0.f;
  #pragma unroll
  for (int kc = 0; kc < 16; ++kc) s += p[(size_t)kc * 16384];
  M[idx] = s * (1.0f / (float)NH);
}

// ---------------------------------------------------------------------------
// C1: K[b,o,i] = sum_j Wz[o,j] * M[b,i,j]
// grid (8, 8 o-chunks of 32), 256 threads
__global__ __launch_bounds__(256) void mk_K(
    const float* __restrict__ M, const float* __restrict__ Wz,
    float* __restrict__ K) {
  const int b = blockIdx.x, o0 = blockIdx.y * 32;
  const int t = threadIdx.x;
  const int i = t & 127, og = (t >> 7) * 16;
  float acc[16] = {};
  const float* mrow = M + ((size_t)b * CI + i) * CI;
  for (int j = 0; j < 128; j += 4) {
    float4 m4 = *(const float4*)&mrow[j];
    #pragma unroll
    for (int o = 0; o < 16; ++o) {
      float4 w4 = *(const float4*)&Wz[(o0 + og + o) * CI + j];
      acc[o] += m4.x * w4.x + m4.y * w4.y + m4.z * w4.z + m4.w * w4.w;
    }
  }
  #pragma unroll
  for (int o = 0; o < 16; ++o)
    K[((size_t)b * NC + o0 + og + o) * CI + i] = acc[o];
}

// ---------------------------------------------------------------------------
// C2: W2[b,o,c] = sum_i K[b,o,i] * Wt[i,c];  b2[b,o] = sum_i K[b,o,i]*bt[i] + bz[o]
// grid (8, 8 o-chunks of 32), 256 threads
__global__ __launch_bounds__(256) void mk_W2(
    const float* __restrict__ K, const float* __restrict__ Wt,
    const float* __restrict__ bt, const float* __restrict__ bz,
    float* __restrict__ W2, float* __restrict__ b2) {
  __shared__ float Ks[32 * 128];
  const int b = blockIdx.x, o0 = blockIdx.y * 32;
  const int t = threadIdx.x;
  #pragma unroll
  for (int k = 0; k < 4; ++k) {
    int f = t + k * 256;                 // 1024 float4 slots
    int o = f >> 5, q = (f & 31) << 2;
    *(float4*)&Ks[o * 128 + q] = *(const float4*)&K[((size_t)b * NC + o0 + o) * CI + q];
  }
  __syncthreads();
  const int c = t;
  float acc[32] = {};
  for (int i = 0; i < 128; i += 4) {
    float w0 = Wt[(i + 0) * 256 + c];
    float w1 = Wt[(i + 1) * 256 + c];
    float w2 = Wt[(i + 2) * 256 + c];
    float w3 = Wt[(i + 3) * 256 + c];
    #pragma unroll
    for (int o = 0; o < 32; ++o) {
      float4 k4 = *(const float4*)&Ks[o * 128 + i];
      acc[o] += k4.x * w0 + k4.y * w1 + k4.z * w2 + k4.w * w3;
    }
  }
  #pragma unroll
  for (int o = 0; o < 32; ++o)
    W2[((size_t)b * NC + o0 + o) * NC + c] = acc[o];
  if (t < 32) {
    float s = 0.f;
    for (int i = 0; i < 128; ++i) s += Ks[t * 128 + i] * bt[i];
    b2[b * NC + o0 + t] = s + bz[o0 + t];
  }
}

// ---------------------------------------------------------------------------
// D: z[b,o,m] = sum_c W2[b,o,c] * xl[b,c,m] + b2[b,o]; accumulate sum/sumsq per b.
// grid (8, 4 o-chunks of 64, 32 m-chunks of 128), 256 threads, 64KB LDS
__global__ __launch_bounds__(256) void mk_z(
    const float* __restrict__ xl, const float* __restrict__ W2,
    const float* __restrict__ b2, float* __restrict__ z,
    float* __restrict__ sums) {
  __shared__ float W2s[64 * 256];        // 64 KB
  const int b = blockIdx.x, o0 = blockIdx.y * 64, m0 = blockIdx.z * 128;
  const int t = threadIdx.x;
  #pragma unroll
  for (int k = 0; k < 16; ++k) {
    int f = t + k * 256;                 // 4096 float4 slots
    int row = f >> 6, q = (f & 63) << 2;
    *(float4*)&W2s[row * 256 + q] = *(const float4*)&W2[((size_t)b * NC + o0 + row) * NC + q];
  }
  __syncthreads();
  const int m = t & 127, grp = (t >> 7) * 32;
  float acc[32] = {};
  const float* xcol = xl + (size_t)b * NC * NL + m0 + m;
  for (int c = 0; c < 256; c += 4) {
    float x0 = xcol[(size_t)(c + 0) * NL];
    float x1 = xcol[(size_t)(c + 1) * NL];
    float x2 = xcol[(size_t)(c + 2) * NL];
    float x3 = xcol[(size_t)(c + 3) * NL];
    #pragma unroll
    for (int o = 0; o < 32; ++o) {
      float4 w4 = *(const float4*)&W2s[(grp + o) * 256 + c];
      acc[o] += w4.x * x0 + w4.y * x1 + w4.z * x2 + w4.w * x3;
    }
  }
  float ls = 0.f, ls2 = 0.f;
  #pragma unroll
  for (int o = 0; o < 32; ++o) {
    float v = acc[o] + b2[b * NC + o0 + grp + o];
    z[((size_t)b * NC + o0 + grp + o) * NL + m0 + m] = v;
    ls += v; ls2 += v * v;
  }
  // block-reduce sum/sumsq, one atomic pair per block
  #pragma unroll
  for (int off = 32; off > 0; off >>= 1) {
    ls += __shfl_down(ls, off);
    ls2 += __shfl_down(ls2, off);
  }
  __syncthreads();                        // done reading W2s; reuse as scratch
  float* red = W2s;
  int wave = t >> 6;
  if ((t & 63) == 0) { red[wave * 2] = ls; red[wave * 2 + 1] = ls2; }
  __syncthreads();
  if (t == 0) {
    float s = red[0] + red[2] + red[4] + red[6];
    float s2 = red[1] + red[3] + red[5] + red[7];
    atomicAdd(&sums[b * 2 + 0], s);
    atomicAdd(&sums[b * 2 + 1], s2);
  }
}

// ---------------------------------------------------------------------------
// E: GroupNorm(1 group) over (C,H,W) per sample + affine
__global__ __launch_bounds__(256) void ln_out(
    const float* __restrict__ z, const float* __restrict__ sums,
    const float* __restrict__ gamma, const float* __restrict__ beta,
    float* __restrict__ out) {
  size_t idx4 = (size_t)blockIdx.x * 256 + threadIdx.x;  // < 2097152
  size_t b = idx4 >> 18;                // 262144 float4 per batch
  size_t rem = idx4 & 262143;
  int o = (int)(rem >> 10);             // 1024 float4 per channel row
  float s = sums[b * 2], s2 = sums[b * 2 + 1];
  const float invN = 1.0f / (float)(NC * NL);
  float mu = s * invN;
  float var = s2 * invN - mu * mu;
  float rs = rsqrtf(var + 1e-5f);
  float ga = gamma[o], be = beta[o];
  float4 v = *(const float4*)&z[idx4 * 4];
  float4 r;
  r.x = (v.x - mu) * rs * ga + be;
  r.y = (v.y - mu) * rs * ga + be;
  r.z = (v.z - mu) * rs * ga + be;
  r.w = (v.w - mu) * rs * ga + be;
  *(float4*)&out[idx4 * 4] = r;
}

// ---------------------------------------------------------------------------
extern "C" void kernel_launch(void* const* d_in, const int* in_sizes, int n_in,
                              void* d_out, int out_size, void* d_ws, size_t ws_size,
                              hipStream_t stream) {
  const float* xh    = (const float*)d_in[0];
  const float* xl    = (const float*)d_in[1];
  const float* Wg    = (const float*)d_in[2];
  const float* bg    = (const float*)d_in[3];
  const float* Wt    = (const float*)d_in[4];
  const float* bt    = (const float*)d_in[5];
  const float* Wp    = (const float*)d_in[6];
  const float* bp    = (const float*)d_in[7];
  const float* Wz    = (const float*)d_in[8];
  const float* bz    = (const float*)d_in[9];
  const float* gamma = (const float*)d_in[10];
  const float* beta  = (const float*)d_in[11];
  float* out = (float*)d_out;
  float* ws = (float*)d_ws;

  // workspace layout (floats); z reuses the phi/g/Mpart/M/K region (dead by then)
  float* phi   = ws + 0;         // 1,048,576
  float* g     = ws + 1048576;   // 1,048,576
  float* Mpart = ws + 2097152;   // 2,097,152
  float* M     = ws + 4194304;   //   131,072
  float* K     = ws + 4325376;   //   262,144
  float* z     = ws + 0;         // 8,388,608 (overlaps dead buffers)
  float* W2    = ws + 8388608;   //   524,288
  float* b2    = ws + 8912896;   //     2,048
  float* sums  = ws + 8914944;   //        16

  hipMemsetAsync(sums, 0, 16 * sizeof(float), stream);

  proj_hi<<<dim3(NB, 8, 8), 256, 0, stream>>>(xh, Wg, bg, Wp, bp, phi, g);
  mk_mpart<<<dim3(NB, 16), 256, 0, stream>>>(phi, g, Mpart);
  mreduce<<<512, 256, 0, stream>>>(Mpart, M);
  mk_K<<<dim3(NB, 8), 256, 0, stream>>>(M, Wz, K);
  mk_W2<<<dim3(NB, 8), 256, 0, stream>>>(K, Wt, bt, bz, W2, b2);
  mk_z<<<dim3(NB, 4, 32), 256, 0, stream>>>(xl, W2, b2, z, sums);
  ln_out<<<8192, 256, 0, stream>>>(z, sums, gamma, beta, out);
}

// Round 7
// 218.986 us; speedup vs baseline: 1.5290x; 1.5290x over previous
//
#include <hip/hip_runtime.h>
#include <hip/hip_bf16.h>

typedef __attribute__((ext_vector_type(8))) short bf16x8;
typedef __attribute__((ext_vector_type(4))) float f32x4;
typedef __attribute__((ext_vector_type(4))) unsigned short us4;
typedef __attribute__((ext_vector_type(8))) unsigned short us8;

#define MFMA(a, b, c) __builtin_amdgcn_mfma_f32_16x16x32_bf16(a, b, c, 0, 0, 0)

__device__ inline unsigned short f2bf(float f) {
  unsigned u = __builtin_bit_cast(unsigned, f);
  u += 0x7FFF + ((u >> 16) & 1);
  return (unsigned short)(u >> 16);
}
__device__ inline float bf2f(unsigned short s) {
  unsigned u = ((unsigned)s) << 16;
  return __builtin_bit_cast(float, u);
}
__device__ inline void gll16(const unsigned short* gsrc, unsigned short* ldst) {
  __builtin_amdgcn_global_load_lds(
      (const __attribute__((address_space(1))) unsigned int*)gsrc,
      (__attribute__((address_space(3))) unsigned int*)ldst, 16, 0, 0);
}

// ---------------------------------------------------------------------------
// Transpose+convert: src f32 [B][256][N] -> dst bf16 [B][N][256]. 64x64 tiles.
__global__ __launch_bounds__(256) void trans_cn(
    const float* __restrict__ src, unsigned short* __restrict__ dst, int N) {
  __shared__ float Ts[64][65];
  const int b = blockIdx.x, c0 = blockIdx.y * 64, n0 = blockIdx.z * 64;
  const int t = threadIdx.x;
  #pragma unroll
  for (int j = 0; j < 4; ++j) {
    int slot = t + j * 256;            // [0,1024) f4 slots: 64 c x 16
    int c = slot >> 4, q = slot & 15;
    float4 v = *(const float4*)&src[((size_t)(b * 256 + c0 + c)) * N + n0 + q * 4];
    Ts[c][q * 4 + 0] = v.x; Ts[c][q * 4 + 1] = v.y;
    Ts[c][q * 4 + 2] = v.z; Ts[c][q * 4 + 3] = v.w;
  }
  __syncthreads();
  #pragma unroll
  for (int rr = 0; rr < 2; ++rr) {
    int n = rr * 32 + (t >> 3), gq = t & 7;
    us8 u;
    #pragma unroll
    for (int k = 0; k < 8; ++k) u[k] = f2bf(Ts[gq * 8 + k][n]);
    *(us8*)&dst[((size_t)(b * N + n0 + n)) * 256 + c0 + gq * 8] = u;
  }
}

// ---------------------------------------------------------------------------
// Convert Wp, Wg (each [128][256] f32) to bf16. grid 32 blocks.
__global__ __launch_bounds__(256) void cvt_w2(
    const float* __restrict__ A, const float* __restrict__ B,
    unsigned short* __restrict__ Ab, unsigned short* __restrict__ Bb) {
  int i = blockIdx.x * 256 + threadIdx.x;    // f4 index, 8192 per tensor
  float4 a = *(const float4*)&A[i * 4];
  float4 b = *(const float4*)&B[i * 4];
  us4 ua, ub;
  ua[0] = f2bf(a.x); ua[1] = f2bf(a.y); ua[2] = f2bf(a.z); ua[3] = f2bf(a.w);
  ub[0] = f2bf(b.x); ub[1] = f2bf(b.y); ub[2] = f2bf(b.z); ub[3] = f2bf(b.w);
  *(us4*)&Ab[i * 4] = ua;
  *(us4*)&Bb[i * 4] = ub;
}

// ---------------------------------------------------------------------------
// phi/g = W{p,g} @ xh + b : MFMA. grid (8, 16). Block: 128 i x 64 n, K=256.
__global__ __launch_bounds__(256) void proj_mfma(
    const unsigned short* __restrict__ xhT,  // [8][1024][256] bf16
    const unsigned short* __restrict__ Wpb, const float* __restrict__ bp,
    const unsigned short* __restrict__ Wgb, const float* __restrict__ bg,
    unsigned short* __restrict__ phi,        // [8][128][1024] bf16
    unsigned short* __restrict__ gg) {
  __shared__ unsigned short Bs[64 * 256];    // 32KB, rows n, 32 granules
  __shared__ unsigned short As[2][128 * 64]; // 2 x 16KB, rows i, 8 granules
  const int b = blockIdx.x, n0 = blockIdx.y * 64;
  const int t = threadIdx.x, lane = t & 63;
  const int wid = t >> 6, wr = wid >> 1, wc = wid & 1;
  #pragma unroll
  for (int j = 0; j < 8; ++j) {              // stage B full-K once
    int slot = t + j * 256;                  // [0,2048): 64 r x 32 g
    int r = slot >> 5, gq = slot & 31;
    gll16(xhT + ((size_t)(b * 1024 + n0 + r)) * 256 + (gq ^ (r & 7)) * 8,
          Bs + slot * 8);
  }
  f32x4 accP[4][2] = {};
  f32x4 accG[4][2] = {};
  for (int kt = 0; kt < 4; ++kt) {
    #pragma unroll
    for (int p = 0; p < 2; ++p) {
      const unsigned short* W = p ? Wgb : Wpb;
      #pragma unroll
      for (int j = 0; j < 4; ++j) {
        int slot = t + j * 256;              // [0,1024): 128 r x 8 g
        int r = slot >> 3, gq = slot & 7;
        gll16(W + (size_t)r * 256 + kt * 64 + (gq ^ (r & 7)) * 8,
              As[p] + slot * 8);
      }
    }
    __syncthreads();
    #pragma unroll
    for (int ks = 0; ks < 2; ++ks) {
      bf16x8 bfr[2];
      #pragma unroll
      for (int fm = 0; fm < 2; ++fm) {
        int r = wc * 32 + fm * 16 + (lane & 15);
        int gc = kt * 8 + ks * 4 + (lane >> 4);
        bfr[fm] = *(const bf16x8*)&Bs[r * 256 + (gc ^ (r & 7)) * 8];
      }
      #pragma unroll
      for (int fo = 0; fo < 4; ++fo) {
        int r = wr * 64 + fo * 16 + (lane & 15);
        int ga = ks * 4 + (lane >> 4);
        bf16x8 ap = *(const bf16x8*)&As[0][r * 64 + (ga ^ (r & 7)) * 8];
        bf16x8 ag = *(const bf16x8*)&As[1][r * 64 + (ga ^ (r & 7)) * 8];
        accP[fo][0] = MFMA(ap, bfr[0], accP[fo][0]);
        accP[fo][1] = MFMA(ap, bfr[1], accP[fo][1]);
        accG[fo][0] = MFMA(ag, bfr[0], accG[fo][0]);
        accG[fo][1] = MFMA(ag, bfr[1], accG[fo][1]);
      }
    }
    __syncthreads();
  }
  #pragma unroll
  for (int fo = 0; fo < 4; ++fo) {
    #pragma unroll
    for (int q = 0; q < 4; ++q) {
      int i = wr * 64 + fo * 16 + (lane >> 4) * 4 + q;
      float vp = bp[i], vg = bg[i];
      #pragma unroll
      for (int fm = 0; fm < 2; ++fm) {
        int n = n0 + wc * 32 + fm * 16 + (lane & 15);
        size_t off = ((size_t)(b * 128 + i)) * 1024 + n;
        phi[off] = f2bf(accP[fo][fm][q] + vp);
        gg[off]  = f2bf(accG[fo][fm][q] + vg);
      }
    }
  }
}

// ---------------------------------------------------------------------------
// Mpart[b][kc][i][j] = sum_{n in chunk of 128} phi[i][n] * g[j][n]. grid (8,8).
__global__ __launch_bounds__(256) void mpart_mfma(
    const unsigned short* __restrict__ phi, const unsigned short* __restrict__ gg,
    float* __restrict__ Mpart) {
  __shared__ unsigned short ps[128 * 128];   // 32KB, rows i, 16 granules
  __shared__ unsigned short gs[128 * 128];
  const int b = blockIdx.x, kc = blockIdx.y;
  const int t = threadIdx.x, lane = t & 63;
  const int wid = t >> 6, wr = wid >> 1, wc = wid & 1;
  #pragma unroll
  for (int j = 0; j < 8; ++j) {
    int slot = t + j * 256;                  // [0,2048): 128 r x 16 g
    int r = slot >> 4, gq = slot & 15;
    size_t src = ((size_t)(b * 128 + r)) * 1024 + kc * 128 + (gq ^ (r & 7)) * 8;
    gll16(phi + src, ps + slot * 8);
    gll16(gg + src, gs + slot * 8);
  }
  __syncthreads();
  f32x4 acc[4][4] = {};
  #pragma unroll
  for (int ks = 0; ks < 4; ++ks) {
    bf16x8 av[4], bv[4];
    #pragma unroll
    for (int f = 0; f < 4; ++f) {
      int ra = wr * 64 + f * 16 + (lane & 15);
      int rb = wc * 64 + f * 16 + (lane & 15);
      int gc = ks * 4 + (lane >> 4);
      av[f] = *(const bf16x8*)&ps[ra * 128 + (gc ^ (ra & 7)) * 8];
      bv[f] = *(const bf16x8*)&gs[rb * 128 + (gc ^ (rb & 7)) * 8];
    }
    #pragma unroll
    for (int i = 0; i < 4; ++i)
      #pragma unroll
      for (int j2 = 0; j2 < 4; ++j2)
        acc[i][j2] = MFMA(av[i], bv[j2], acc[i][j2]);
  }
  float* mp = Mpart + ((size_t)(b * 8 + kc)) * 128 * 128;
  #pragma unroll
  for (int i = 0; i < 4; ++i)
    #pragma unroll
    for (int q = 0; q < 4; ++q) {
      int ii = wr * 64 + i * 16 + (lane >> 4) * 4 + q;
      #pragma unroll
      for (int j2 = 0; j2 < 4; ++j2) {
        int jj = wc * 64 + j2 * 16 + (lane & 15);
        mp[ii * 128 + jj] = acc[i][j2][q];
      }
    }
}

// ---------------------------------------------------------------------------
// M = (1/1024) * sum_kc Mpart. grid 128.
__global__ __launch_bounds__(256) void mreduce(
    const float* __restrict__ Mpart, float* __restrict__ M) {
  int i4 = blockIdx.x * 256 + threadIdx.x;   // [0, 32768)
  int b = i4 >> 12, r4 = i4 & 4095;
  const float4* p = (const float4*)Mpart + (size_t)b * 8 * 4096 + r4;
  float4 s = {0.f, 0.f, 0.f, 0.f};
  #pragma unroll
  for (int kc = 0; kc < 8; ++kc) {
    float4 v = p[(size_t)kc * 4096];
    s.x += v.x; s.y += v.y; s.z += v.z; s.w += v.w;
  }
  const float sc = 1.0f / 1024.0f;
  s.x *= sc; s.y *= sc; s.z *= sc; s.w *= sc;
  ((float4*)M)[i4] = s;
}

// ---------------------------------------------------------------------------
// K[b,o,i] = sum_j Wz[o,j] * M[b,i,j]. grid (8, 8). (fp32, small)
__global__ __launch_bounds__(256) void mk_K(
    const float* __restrict__ M, const float* __restrict__ Wz,
    float* __restrict__ K) {
  const int b = blockIdx.x, o0 = blockIdx.y * 32;
  const int t = threadIdx.x;
  const int i = t & 127, og = (t >> 7) * 16;
  float acc[16] = {};
  const float* mrow = M + ((size_t)(b * 128 + i)) * 128;
  for (int j = 0; j < 128; j += 4) {
    float4 m4 = *(const float4*)&mrow[j];
    #pragma unroll
    for (int o = 0; o < 16; ++o) {
      float4 w4 = *(const float4*)&Wz[(o0 + og + o) * 128 + j];
      acc[o] += m4.x * w4.x + m4.y * w4.y + m4.z * w4.z + m4.w * w4.w;
    }
  }
  #pragma unroll
  for (int o = 0; o < 16; ++o)
    K[((size_t)(b * 256 + o0 + og + o)) * 128 + i] = acc[o];
}

// ---------------------------------------------------------------------------
// W2b[b,o,c] (bf16) = sum_i K[b,o,i]*Wt[i,c]; b2[b,o] = sum_i K*bt + bz. grid (8,8)
__global__ __launch_bounds__(256) void mk_W2(
    const float* __restrict__ K, const float* __restrict__ Wt,
    const float* __restrict__ bt, const float* __restrict__ bz,
    unsigned short* __restrict__ W2b, float* __restrict__ b2) {
  __shared__ float Ks[32 * 128];
  const int b = blockIdx.x, o0 = blockIdx.y * 32;
  const int t = threadIdx.x;
  #pragma unroll
  for (int k = 0; k < 4; ++k) {
    int f = t + k * 256;                     // 1024 f4 slots
    int o = f >> 5, q = (f & 31) << 2;
    *(float4*)&Ks[o * 128 + q] = *(const float4*)&K[((size_t)(b * 256 + o0 + o)) * 128 + q];
  }
  __syncthreads();
  const int c = t;
  float acc[32] = {};
  for (int i = 0; i < 128; i += 4) {
    float w0 = Wt[(i + 0) * 256 + c];
    float w1 = Wt[(i + 1) * 256 + c];
    float w2 = Wt[(i + 2) * 256 + c];
    float w3 = Wt[(i + 3) * 256 + c];
    #pragma unroll
    for (int o = 0; o < 32; ++o) {
      float4 k4 = *(const float4*)&Ks[o * 128 + i];
      acc[o] += k4.x * w0 + k4.y * w1 + k4.z * w2 + k4.w * w3;
    }
  }
  #pragma unroll
  for (int o = 0; o < 32; ++o)
    W2b[((size_t)(b * 256 + o0 + o)) * 256 + c] = f2bf(acc[o]);
  if (t < 32) {
    float s = 0.f;
    for (int i = 0; i < 128; ++i) s += Ks[t * 128 + i] * bt[i];
    b2[b * 256 + o0 + t] = s + bz[o0 + t];
  }
}

// ---------------------------------------------------------------------------
// z = W2 @ xl + b2 (MFMA, bf16 out) + per-batch sum/sumsq. grid (8, 2, 32).
__global__ __launch_bounds__(256) void mk_z_mfma(
    const unsigned short* __restrict__ xlT,  // [8][4096][256] bf16
    const unsigned short* __restrict__ W2b,  // [8][256][256] bf16
    const float* __restrict__ b2,
    unsigned short* __restrict__ z,          // [8][256][4096] bf16
    float* __restrict__ sums) {
  __shared__ unsigned short As[128 * 64];    // 16KB, rows o, 8 granules
  __shared__ unsigned short Bs[128 * 64];    // 16KB, rows m
  __shared__ float red[8];
  const int b = blockIdx.x, ot = blockIdx.y, mt = blockIdx.z;
  const int t = threadIdx.x, lane = t & 63;
  const int wid = t >> 6, wr = wid >> 1, wc = wid & 1;
  f32x4 acc[4][4] = {};
  for (int kt = 0; kt < 4; ++kt) {
    #pragma unroll
    for (int j = 0; j < 4; ++j) {
      int slot = t + j * 256;                // [0,1024): 128 r x 8 g
      int r = slot >> 3, gq = slot & 7;
      int cg = kt * 64 + (gq ^ (r & 7)) * 8;
      gll16(W2b + ((size_t)(b * 256 + ot * 128 + r)) * 256 + cg, As + slot * 8);
      gll16(xlT + ((size_t)(b * 4096 + mt * 128 + r)) * 256 + cg, Bs + slot * 8);
    }
    __syncthreads();
    #pragma unroll
    for (int ks = 0; ks < 2; ++ks) {
      bf16x8 av[4], bv[4];
      #pragma unroll
      for (int f = 0; f < 4; ++f) {
        int ra = wr * 64 + f * 16 + (lane & 15);
        int rb = wc * 64 + f * 16 + (lane & 15);
        int gc = ks * 4 + (lane >> 4);
        av[f] = *(const bf16x8*)&As[ra * 64 + (gc ^ (ra & 7)) * 8];
        bv[f] = *(const bf16x8*)&Bs[rb * 64 + (gc ^ (rb & 7)) * 8];
      }
      #pragma unroll
      for (int i = 0; i < 4; ++i)
        #pragma unroll
        for (int j2 = 0; j2 < 4; ++j2)
          acc[i][j2] = MFMA(av[i], bv[j2], acc[i][j2]);
    }
    __syncthreads();
  }
  float ls = 0.f, ls2 = 0.f;
  #pragma unroll
  for (int i = 0; i < 4; ++i) {
    #pragma unroll
    for (int q = 0; q < 4; ++q) {
      int o = ot * 128 + wr * 64 + i * 16 + (lane >> 4) * 4 + q;
      float bias = b2[b * 256 + o];
      #pragma unroll
      for (int j2 = 0; j2 < 4; ++j2) {
        int m = mt * 128 + wc * 64 + j2 * 16 + (lane & 15);
        float v = acc[i][j2][q] + bias;
        z[((size_t)(b * 256 + o)) * 4096 + m] = f2bf(v);
        ls += v; ls2 += v * v;
      }
    }
  }
  #pragma unroll
  for (int off = 32; off > 0; off >>= 1) {
    ls  += __shfl_down(ls, off);
    ls2 += __shfl_down(ls2, off);
  }
  if ((t & 63) == 0) { red[wid * 2] = ls; red[wid * 2 + 1] = ls2; }
  __syncthreads();
  if (t == 0) {
    atomicAdd(&sums[b * 2 + 0], red[0] + red[2] + red[4] + red[6]);
    atomicAdd(&sums[b * 2 + 1], red[1] + red[3] + red[5] + red[7]);
  }
}

// ---------------------------------------------------------------------------
// GroupNorm(1) + affine: out f32 from z bf16. grid 4096.
__global__ __launch_bounds__(256) void ln_out(
    const unsigned short* __restrict__ z, const float* __restrict__ sums,
    const float* __restrict__ gamma, const float* __restrict__ beta,
    float* __restrict__ out) {
  size_t i8 = (size_t)blockIdx.x * 256 + threadIdx.x;   // [0, 1048576)
  int b = (int)(i8 >> 17);
  int o = (int)((i8 >> 9) & 255);
  float s = sums[b * 2], s2 = sums[b * 2 + 1];
  const float invN = 1.0f / (256.0f * 4096.0f);
  float mu = s * invN;
  float var = s2 * invN - mu * mu;
  float rs = rsqrtf(var + 1e-5f);
  float ga = gamma[o] * rs;
  float be = beta[o] - mu * rs * gamma[o];
  us8 u = *(const us8*)&z[i8 * 8];
  float4 r0, r1;
  r0.x = bf2f(u[0]) * ga + be; r0.y = bf2f(u[1]) * ga + be;
  r0.z = bf2f(u[2]) * ga + be; r0.w = bf2f(u[3]) * ga + be;
  r1.x = bf2f(u[4]) * ga + be; r1.y = bf2f(u[5]) * ga + be;
  r1.z = bf2f(u[6]) * ga + be; r1.w = bf2f(u[7]) * ga + be;
  *(float4*)&out[i8 * 8] = r0;
  *(float4*)&out[i8 * 8 + 4] = r1;
}

// ---------------------------------------------------------------------------
extern "C" void kernel_launch(void* const* d_in, const int* in_sizes, int n_in,
                              void* d_out, int out_size, void* d_ws, size_t ws_size,
                              hipStream_t stream) {
  const float* xh    = (const float*)d_in[0];
  const float* xl    = (const float*)d_in[1];
  const float* Wg    = (const float*)d_in[2];
  const float* bg    = (const float*)d_in[3];
  const float* Wt    = (const float*)d_in[4];
  const float* bt    = (const float*)d_in[5];
  const float* Wp    = (const float*)d_in[6];
  const float* bp    = (const float*)d_in[7];
  const float* Wz    = (const float*)d_in[8];
  const float* bz    = (const float*)d_in[9];
  const float* gamma = (const float*)d_in[10];
  const float* beta  = (const float*)d_in[11];
  float* out = (float*)d_out;
  float* ws = (float*)d_ws;

  // ws layout (float slots). z overlaps the early-pipeline buffers (all dead
  // before mk_z writes). Peak = 8,685,584 floats = 34.7 MB.
  unsigned short* xhT  = (unsigned short*)(ws + 0);        // 2,097,152 bf16
  unsigned short* phi  = (unsigned short*)(ws + 1048576);  // 1,048,576 bf16
  unsigned short* gbuf = (unsigned short*)(ws + 1572864);  // 1,048,576 bf16
  float* Mpart = ws + 2097152;                             // 1,048,576 f32
  float* M     = ws + 3145728;                             //   131,072 f32
  float* K     = ws + 3276800;                             //   262,144 f32
  unsigned short* zbuf = (unsigned short*)(ws + 0);        // 8,388,608 bf16
  unsigned short* xlT  = (unsigned short*)(ws + 4194304);  // 8,388,608 bf16
  unsigned short* W2b  = (unsigned short*)(ws + 8388608);  //   524,288 bf16
  float* b2    = ws + 8650752;                             //     2,048 f32
  float* sums  = ws + 8652800;                             //        16 f32
  unsigned short* Wpb  = (unsigned short*)(ws + 8652816);  //    32,768 bf16
  unsigned short* Wgb  = (unsigned short*)(ws + 8669200);  //    32,768 bf16

  hipMemsetAsync(sums, 0, 16 * sizeof(float), stream);

  trans_cn<<<dim3(8, 4, 16), 256, 0, stream>>>(xh, xhT, 1024);
  trans_cn<<<dim3(8, 4, 64), 256, 0, stream>>>(xl, xlT, 4096);
  cvt_w2<<<32, 256, 0, stream>>>(Wp, Wg, Wpb, Wgb);
  proj_mfma<<<dim3(8, 16), 256, 0, stream>>>(xhT, Wpb, bp, Wgb, bg, phi, gbuf);
  mpart_mfma<<<dim3(8, 8), 256, 0, stream>>>(phi, gbuf, Mpart);
  mreduce<<<128, 256, 0, stream>>>(Mpart, M);
  mk_K<<<dim3(8, 8), 256, 0, stream>>>(M, Wz, K);
  mk_W2<<<dim3(8, 8), 256, 0, stream>>>(K, Wt, bt, bz, W2b, b2);
  mk_z_mfma<<<dim3(8, 2, 32), 256, 0, stream>>>(xlT, W2b, b2, zbuf, sums);
  ln_out<<<4096, 256, 0, stream>>>(zbuf, sums, gamma, beta, out);
}

// Round 8
// 207.285 us; speedup vs baseline: 1.6153x; 1.0565x over previous
//
#include <hip/hip_runtime.h>
#include <hip/hip_bf16.h>

typedef __attribute__((ext_vector_type(8))) short bf16x8;
typedef __attribute__((ext_vector_type(4))) float f32x4;
typedef __attribute__((ext_vector_type(4))) unsigned short us4;
typedef __attribute__((ext_vector_type(8))) unsigned short us8;

#define MFMA(a, b, c) __builtin_amdgcn_mfma_f32_16x16x32_bf16(a, b, c, 0, 0, 0)

__device__ inline unsigned short f2bf(float f) {
  unsigned u = __builtin_bit_cast(unsigned, f);
  u += 0x7FFF + ((u >> 16) & 1);
  return (unsigned short)(u >> 16);
}
__device__ inline float bf2f(unsigned short s) {
  unsigned u = ((unsigned)s) << 16;
  return __builtin_bit_cast(float, u);
}
__device__ inline unsigned pack2(float lo, float hi) {
  return (unsigned)f2bf(lo) | ((unsigned)f2bf(hi) << 16);
}
__device__ inline void gll16(const unsigned short* gsrc, unsigned short* ldst) {
  __builtin_amdgcn_global_load_lds(
      (const __attribute__((address_space(1))) unsigned int*)gsrc,
      (__attribute__((address_space(3))) unsigned int*)ldst, 16, 0, 0);
}

// ---------------------------------------------------------------------------
// Convert Wp, Wg (each [128][256] f32) to bf16. grid 32 blocks.
__global__ __launch_bounds__(256) void cvt_w2(
    const float* __restrict__ A, const float* __restrict__ B,
    unsigned short* __restrict__ Ab, unsigned short* __restrict__ Bb) {
  int i = blockIdx.x * 256 + threadIdx.x;    // f4 index, 8192 per tensor
  float4 a = *(const float4*)&A[i * 4];
  float4 b = *(const float4*)&B[i * 4];
  us4 ua, ub;
  ua[0] = f2bf(a.x); ua[1] = f2bf(a.y); ua[2] = f2bf(a.z); ua[3] = f2bf(a.w);
  ub[0] = f2bf(b.x); ub[1] = f2bf(b.y); ub[2] = f2bf(b.z); ub[3] = f2bf(b.w);
  *(us4*)&Ab[i * 4] = ua;
  *(us4*)&Bb[i * 4] = ub;
}

// ---------------------------------------------------------------------------
// phi/g = W{p,g} @ xh + b, reading xh f32 DIRECTLY (transpose+cvt in LDS).
// grid (8, 16). Block: 128 i x 64 n, K=256.
__global__ __launch_bounds__(256) void proj_f(
    const float* __restrict__ xh,            // [8][256][1024] f32
    const unsigned short* __restrict__ Wpb, const float* __restrict__ bp,
    const unsigned short* __restrict__ Wgb, const float* __restrict__ bg,
    unsigned short* __restrict__ phi,        // [8][128][1024] bf16
    unsigned short* __restrict__ gg) {
  __shared__ unsigned short Bs[64 * 256];    // 32KB [n][c], granule-swizzled
  __shared__ unsigned short As[2][128 * 64]; // 2 x 16KB [i][c-chunk]
  const int b = blockIdx.x, n0 = blockIdx.y * 64;
  const int t = threadIdx.x, lane = t & 63;
  const int wid = t >> 6, wr = wid >> 1, wc = wid & 1;
  // B-stage: transpose-convert xh[256c][64n] -> Bs[n][256c] bf16.
  // slot s: bits s[2:0]=nf[2:0], s[9:3]=c2, s[10]=nf[3]. 2048 slots.
  #pragma unroll
  for (int it = 0; it < 8; ++it) {
    int s = it * 256 + t;
    int nf = (s & 7) | ((s >> 10) << 3);     // 0..15 (m-f4 index)
    int c2 = (s >> 3) & 127;                 // c = 2*c2
    const float* p = xh + ((size_t)(b * 256 + 2 * c2)) * 1024 + n0 + nf * 4;
    float4 a = *(const float4*)p;
    float4 bq = *(const float4*)(p + 1024);
    const float* ap = (const float*)&a;
    const float* bp2 = (const float*)&bq;
    #pragma unroll
    for (int i = 0; i < 4; ++i) {
      int n = nf * 4 + i;
      int col32 = (((c2 >> 2) ^ (n & 7)) << 2) | (c2 & 3);  // 0..127
      ((unsigned*)Bs)[n * 128 + col32] = pack2(ap[i], bp2[i]);
    }
  }
  f32x4 accP[4][2] = {};
  f32x4 accG[4][2] = {};
  for (int kt = 0; kt < 4; ++kt) {
    #pragma unroll
    for (int p = 0; p < 2; ++p) {
      const unsigned short* W = p ? Wgb : Wpb;
      #pragma unroll
      for (int j = 0; j < 4; ++j) {
        int slot = t + j * 256;              // [0,1024): 128 r x 8 g
        int r = slot >> 3, gq = slot & 7;
        gll16(W + (size_t)r * 256 + kt * 64 + (gq ^ (r & 7)) * 8,
              As[p] + slot * 8);
      }
    }
    __syncthreads();
    #pragma unroll
    for (int ks = 0; ks < 2; ++ks) {
      bf16x8 bfr[2];
      #pragma unroll
      for (int fm = 0; fm < 2; ++fm) {
        int r = wc * 32 + fm * 16 + (lane & 15);
        int gc = kt * 8 + ks * 4 + (lane >> 4);
        bfr[fm] = *(const bf16x8*)&Bs[r * 256 + (gc ^ (r & 7)) * 8];
      }
      #pragma unroll
      for (int fo = 0; fo < 4; ++fo) {
        int r = wr * 64 + fo * 16 + (lane & 15);
        int ga = ks * 4 + (lane >> 4);
        bf16x8 ap = *(const bf16x8*)&As[0][r * 64 + (ga ^ (r & 7)) * 8];
        bf16x8 ag = *(const bf16x8*)&As[1][r * 64 + (ga ^ (r & 7)) * 8];
        accP[fo][0] = MFMA(ap, bfr[0], accP[fo][0]);
        accP[fo][1] = MFMA(ap, bfr[1], accP[fo][1]);
        accG[fo][0] = MFMA(ag, bfr[0], accG[fo][0]);
        accG[fo][1] = MFMA(ag, bfr[1], accG[fo][1]);
      }
    }
    __syncthreads();
  }
  #pragma unroll
  for (int fo = 0; fo < 4; ++fo) {
    #pragma unroll
    for (int q = 0; q < 4; ++q) {
      int i = wr * 64 + fo * 16 + (lane >> 4) * 4 + q;
      float vp = bp[i], vg = bg[i];
      #pragma unroll
      for (int fm = 0; fm < 2; ++fm) {
        int n = n0 + wc * 32 + fm * 16 + (lane & 15);
        size_t off = ((size_t)(b * 128 + i)) * 1024 + n;
        phi[off] = f2bf(accP[fo][fm][q] + vp);
        gg[off]  = f2bf(accG[fo][fm][q] + vg);
      }
    }
  }
}

// ---------------------------------------------------------------------------
// Mpart[b][kc][i][j] = sum_{n in chunk of 128} phi[i][n] * g[j][n]. grid (8,8).
__global__ __launch_bounds__(256) void mpart_mfma(
    const unsigned short* __restrict__ phi, const unsigned short* __restrict__ gg,
    float* __restrict__ Mpart) {
  __shared__ unsigned short ps[128 * 128];   // 32KB, rows i, 16 granules
  __shared__ unsigned short gs[128 * 128];
  const int b = blockIdx.x, kc = blockIdx.y;
  const int t = threadIdx.x, lane = t & 63;
  const int wid = t >> 6, wr = wid >> 1, wc = wid & 1;
  #pragma unroll
  for (int j = 0; j < 8; ++j) {
    int slot = t + j * 256;                  // [0,2048): 128 r x 16 g
    int r = slot >> 4, gq = slot & 15;
    size_t src = ((size_t)(b * 128 + r)) * 1024 + kc * 128 + (gq ^ (r & 7)) * 8;
    gll16(phi + src, ps + slot * 8);
    gll16(gg + src, gs + slot * 8);
  }
  __syncthreads();
  f32x4 acc[4][4] = {};
  #pragma unroll
  for (int ks = 0; ks < 4; ++ks) {
    bf16x8 av[4], bv[4];
    #pragma unroll
    for (int f = 0; f < 4; ++f) {
      int ra = wr * 64 + f * 16 + (lane & 15);
      int rb = wc * 64 + f * 16 + (lane & 15);
      int gc = ks * 4 + (lane >> 4);
      av[f] = *(const bf16x8*)&ps[ra * 128 + (gc ^ (ra & 7)) * 8];
      bv[f] = *(const bf16x8*)&gs[rb * 128 + (gc ^ (rb & 7)) * 8];
    }
    #pragma unroll
    for (int i = 0; i < 4; ++i)
      #pragma unroll
      for (int j2 = 0; j2 < 4; ++j2)
        acc[i][j2] = MFMA(av[i], bv[j2], acc[i][j2]);
  }
  float* mp = Mpart + ((size_t)(b * 8 + kc)) * 128 * 128;
  #pragma unroll
  for (int i = 0; i < 4; ++i)
    #pragma unroll
    for (int q = 0; q < 4; ++q) {
      int ii = wr * 64 + i * 16 + (lane >> 4) * 4 + q;
      #pragma unroll
      for (int j2 = 0; j2 < 4; ++j2) {
        int jj = wc * 64 + j2 * 16 + (lane & 15);
        mp[ii * 128 + jj] = acc[i][j2][q];
      }
    }
}

// ---------------------------------------------------------------------------
// M = (1/1024) * sum_kc Mpart. grid 128.
__global__ __launch_bounds__(256) void mreduce(
    const float* __restrict__ Mpart, float* __restrict__ M) {
  int i4 = blockIdx.x * 256 + threadIdx.x;   // [0, 32768)
  int b = i4 >> 12, r4 = i4 & 4095;
  const float4* p = (const float4*)Mpart + (size_t)b * 8 * 4096 + r4;
  float4 s = {0.f, 0.f, 0.f, 0.f};
  #pragma unroll
  for (int kc = 0; kc < 8; ++kc) {
    float4 v = p[(size_t)kc * 4096];
    s.x += v.x; s.y += v.y; s.z += v.z; s.w += v.w;
  }
  const float sc = 1.0f / 1024.0f;
  s.x *= sc; s.y *= sc; s.z *= sc; s.w *= sc;
  ((float4*)M)[i4] = s;
}

// ---------------------------------------------------------------------------
// K[b,o,i] = sum_j Wz[o,j] * M[b,i,j]. grid (8, 8). (fp32, small)
__global__ __launch_bounds__(256) void mk_K(
    const float* __restrict__ M, const float* __restrict__ Wz,
    float* __restrict__ K) {
  const int b = blockIdx.x, o0 = blockIdx.y * 32;
  const int t = threadIdx.x;
  const int i = t & 127, og = (t >> 7) * 16;
  float acc[16] = {};
  const float* mrow = M + ((size_t)(b * 128 + i)) * 128;
  for (int j = 0; j < 128; j += 4) {
    float4 m4 = *(const float4*)&mrow[j];
    #pragma unroll
    for (int o = 0; o < 16; ++o) {
      float4 w4 = *(const float4*)&Wz[(o0 + og + o) * 128 + j];
      acc[o] += m4.x * w4.x + m4.y * w4.y + m4.z * w4.z + m4.w * w4.w;
    }
  }
  #pragma unroll
  for (int o = 0; o < 16; ++o)
    K[((size_t)(b * 256 + o0 + og + o)) * 128 + i] = acc[o];
}

// ---------------------------------------------------------------------------
// W2b[b,o,c] (bf16) = sum_i K[b,o,i]*Wt[i,c]; b2[b,o] = sum_i K*bt + bz. grid (8,8)
__global__ __launch_bounds__(256) void mk_W2(
    const float* __restrict__ K, const float* __restrict__ Wt,
    const float* __restrict__ bt, const float* __restrict__ bz,
    unsigned short* __restrict__ W2b, float* __restrict__ b2) {
  __shared__ float Ks[32 * 128];
  const int b = blockIdx.x, o0 = blockIdx.y * 32;
  const int t = threadIdx.x;
  #pragma unroll
  for (int k = 0; k < 4; ++k) {
    int f = t + k * 256;                     // 1024 f4 slots
    int o = f >> 5, q = (f & 31) << 2;
    *(float4*)&Ks[o * 128 + q] = *(const float4*)&K[((size_t)(b * 256 + o0 + o)) * 128 + q];
  }
  __syncthreads();
  const int c = t;
  float acc[32] = {};
  for (int i = 0; i < 128; i += 4) {
    float w0 = Wt[(i + 0) * 256 + c];
    float w1 = Wt[(i + 1) * 256 + c];
    float w2 = Wt[(i + 2) * 256 + c];
    float w3 = Wt[(i + 3) * 256 + c];
    #pragma unroll
    for (int o = 0; o < 32; ++o) {
      float4 k4 = *(const float4*)&Ks[o * 128 + i];
      acc[o] += k4.x * w0 + k4.y * w1 + k4.z * w2 + k4.w * w3;
    }
  }
  #pragma unroll
  for (int o = 0; o < 32; ++o)
    W2b[((size_t)(b * 256 + o0 + o)) * 256 + c] = f2bf(acc[o]);
  if (t < 32) {
    float s = 0.f;
    for (int i = 0; i < 128; ++i) s += Ks[t * 128 + i] * bt[i];
    b2[b * 256 + o0 + t] = s + bz[o0 + t];
  }
}

// ---------------------------------------------------------------------------
// z = W2 @ xl + b2 reading xl f32 DIRECTLY (transpose+cvt in LDS).
// grid (8, 64): block = 256 o x 64 m, K=256 in 4 steps of 64.
__global__ __launch_bounds__(256) void mk_z_f(
    const float* __restrict__ xl,            // [8][256][4096] f32
    const unsigned short* __restrict__ W2b,  // [8][256][256] bf16
    const float* __restrict__ b2,
    unsigned short* __restrict__ z,          // [8][256][4096] bf16
    float* __restrict__ sums) {
  __shared__ unsigned short As[256 * 64];    // 32KB [o][c-chunk]
  __shared__ unsigned short Bs[64 * 64];     // 8KB  [m][c-chunk], swizzled
  __shared__ float red[8];
  const int b = blockIdx.x, m0 = blockIdx.y * 64;
  const int t = threadIdx.x, lane = t & 63;
  const int w = t >> 6;                      // wave 0..3 -> o-range w*64
  f32x4 acc[4][4] = {};                      // [o-frag][m-frag]
  for (int kt = 0; kt < 4; ++kt) {
    // A: W2b[o][kt*64..] via global_load_lds, 2048 slots (256 r x 8 g)
    #pragma unroll
    for (int j = 0; j < 8; ++j) {
      int slot = t + j * 256;
      int r = slot >> 3, gq = slot & 7;
      gll16(W2b + ((size_t)(b * 256 + r)) * 256 + kt * 64 + (gq ^ (r & 7)) * 8,
            As + slot * 8);
    }
    // B: transpose-convert xl[kt*64..][m0..m0+64] f32 -> Bs[m][c] bf16
    // slot s: s[2:0]=mf[2:0], s[7:3]=c2, s[8]=mf[3]. 512 slots.
    #pragma unroll
    for (int it = 0; it < 2; ++it) {
      int s = it * 256 + t;
      int mf = (s & 7) | ((s >> 8) << 3);    // 0..15
      int c2 = (s >> 3) & 31;                // c = 2*c2 in [0,64)
      const float* p = xl + ((size_t)(b * 256 + kt * 64 + 2 * c2)) * 4096 + m0 + mf * 4;
      float4 a = *(const float4*)p;
      float4 bq = *(const float4*)(p + 4096);
      const float* ap = (const float*)&a;
      const float* bp2 = (const float*)&bq;
      #pragma unroll
      for (int i = 0; i < 4; ++i) {
        int m = mf * 4 + i;
        int col32 = (((c2 >> 2) ^ (m & 7)) << 2) | (c2 & 3);  // 0..31
        ((unsigned*)Bs)[m * 32 + col32] = pack2(ap[i], bp2[i]);
      }
    }
    __syncthreads();
    #pragma unroll
    for (int ks = 0; ks < 2; ++ks) {
      bf16x8 av[4], bv[4];
      #pragma unroll
      for (int f = 0; f < 4; ++f) {
        int ra = w * 64 + f * 16 + (lane & 15);   // o row
        int rb = f * 16 + (lane & 15);            // m row
        int gc = ks * 4 + (lane >> 4);
        av[f] = *(const bf16x8*)&As[ra * 64 + (gc ^ (ra & 7)) * 8];
        bv[f] = *(const bf16x8*)&Bs[rb * 64 + (gc ^ (rb & 7)) * 8];
      }
      #pragma unroll
      for (int i = 0; i < 4; ++i)
        #pragma unroll
        for (int j2 = 0; j2 < 4; ++j2)
          acc[i][j2] = MFMA(av[i], bv[j2], acc[i][j2]);
    }
    __syncthreads();
  }
  float ls = 0.f, ls2 = 0.f;
  #pragma unroll
  for (int i = 0; i < 4; ++i) {
    #pragma unroll
    for (int q = 0; q < 4; ++q) {
      int o = w * 64 + i * 16 + (lane >> 4) * 4 + q;
      float bias = b2[b * 256 + o];
      #pragma unroll
      for (int j2 = 0; j2 < 4; ++j2) {
        int m = m0 + j2 * 16 + (lane & 15);
        float v = acc[i][j2][q] + bias;
        z[((size_t)(b * 256 + o)) * 4096 + m] = f2bf(v);
        ls += v; ls2 += v * v;
      }
    }
  }
  #pragma unroll
  for (int off = 32; off > 0; off >>= 1) {
    ls  += __shfl_down(ls, off);
    ls2 += __shfl_down(ls2, off);
  }
  if ((t & 63) == 0) { red[w * 2] = ls; red[w * 2 + 1] = ls2; }
  __syncthreads();
  if (t == 0) {
    atomicAdd(&sums[b * 2 + 0], red[0] + red[2] + red[4] + red[6]);
    atomicAdd(&sums[b * 2 + 1], red[1] + red[3] + red[5] + red[7]);
  }
}

// ---------------------------------------------------------------------------
// GroupNorm(1) + affine: out f32 from z bf16. grid 4096.
__global__ __launch_bounds__(256) void ln_out(
    const unsigned short* __restrict__ z, const float* __restrict__ sums,
    const float* __restrict__ gamma, const float* __restrict__ beta,
    float* __restrict__ out) {
  size_t i8 = (size_t)blockIdx.x * 256 + threadIdx.x;   // [0, 1048576)
  int b = (int)(i8 >> 17);
  int o = (int)((i8 >> 9) & 255);
  float s = sums[b * 2], s2 = sums[b * 2 + 1];
  const float invN = 1.0f / (256.0f * 4096.0f);
  float mu = s * invN;
  float var = s2 * invN - mu * mu;
  float rs = rsqrtf(var + 1e-5f);
  float ga = gamma[o] * rs;
  float be = beta[o] - mu * rs * gamma[o];
  us8 u = *(const us8*)&z[i8 * 8];
  float4 r0, r1;
  r0.x = bf2f(u[0]) * ga + be; r0.y = bf2f(u[1]) * ga + be;
  r0.z = bf2f(u[2]) * ga + be; r0.w = bf2f(u[3]) * ga + be;
  r1.x = bf2f(u[4]) * ga + be; r1.y = bf2f(u[5]) * ga + be;
  r1.z = bf2f(u[6]) * ga + be; r1.w = bf2f(u[7]) * ga + be;
  *(float4*)&out[i8 * 8] = r0;
  *(float4*)&out[i8 * 8 + 4] = r1;
}

// ---------------------------------------------------------------------------
extern "C" void kernel_launch(void* const* d_in, const int* in_sizes, int n_in,
                              void* d_out, int out_size, void* d_ws, size_t ws_size,
                              hipStream_t stream) {
  const float* xh    = (const float*)d_in[0];
  const float* xl    = (const float*)d_in[1];
  const float* Wg    = (const float*)d_in[2];
  const float* bg    = (const float*)d_in[3];
  const float* Wt    = (const float*)d_in[4];
  const float* bt    = (const float*)d_in[5];
  const float* Wp    = (const float*)d_in[6];
  const float* bp    = (const float*)d_in[7];
  const float* Wz    = (const float*)d_in[8];
  const float* bz    = (const float*)d_in[9];
  const float* gamma = (const float*)d_in[10];
  const float* beta  = (const float*)d_in[11];
  float* out = (float*)d_out;
  float* ws = (float*)d_ws;

  // ws layout (float slots), non-overlapping. Peak ~14.2M floats = 57MB?
  // No: zbuf 8.4M + others ~3.6M = 12M floats = 48MB... keep within prior
  // footprint by overlapping zbuf with phi/g/Mpart (dead before mk_z_f).
  unsigned short* phi  = (unsigned short*)(ws + 0);        // 1,048,576 bf16
  unsigned short* gbuf = (unsigned short*)(ws + 524288);   // 1,048,576 bf16
  float* Mpart = ws + 1048576;                             // 1,048,576 f32
  float* M     = ws + 2097152;                             //   131,072 f32
  float* K     = ws + 2228224;                             //   262,144 f32
  unsigned short* zbuf = (unsigned short*)(ws + 0);        // 8,388,608 bf16 (overlaps phi/g/Mpart — dead)
  unsigned short* W2b  = (unsigned short*)(ws + 4194304);  //   524,288 bf16
  float* b2    = ws + 4456448;                             //     2,048 f32
  float* sums  = ws + 4458496;                             //        16 f32
  unsigned short* Wpb  = (unsigned short*)(ws + 4458512);  //    32,768 bf16
  unsigned short* Wgb  = (unsigned short*)(ws + 4474896);  //    32,768 bf16

  hipMemsetAsync(sums, 0, 16 * sizeof(float), stream);

  cvt_w2<<<32, 256, 0, stream>>>(Wp, Wg, Wpb, Wgb);
  proj_f<<<dim3(8, 16), 256, 0, stream>>>(xh, Wpb, bp, Wgb, bg, phi, gbuf);
  mpart_mfma<<<dim3(8, 8), 256, 0, stream>>>(phi, gbuf, Mpart);
  mreduce<<<128, 256, 0, stream>>>(Mpart, M);
  mk_K<<<dim3(8, 8), 256, 0, stream>>>(M, Wz, K);
  mk_W2<<<dim3(8, 8), 256, 0, stream>>>(K, Wt, bt, bz, W2b, b2);
  mk_z_f<<<dim3(8, 64), 256, 0, stream>>>(xl, W2b, b2, zbuf, sums);
  ln_out<<<4096, 256, 0, stream>>>(zbuf, sums, gamma, beta, out);
}